// Round 4
// baseline (87.885 us; speedup 1.0000x reference)
//
#include <hip/hip_runtime.h>
#include <math.h>

#define BATCH 16
#define N_ROIS 1000
#define NUM_CLASSES 81
#define DET_MAX 100
#define MIN_CONF 0.7f
#define NMS_THRESH 0.3f

#define NTHREADS 512
#define SUP_WORDS 4           // 256-bit suppression rows; serial fallback if m>256

// Single fused kernel, one block per batch image, 512 threads.
// Phase A: per-thread argmax over the ROI's 81 probs read DIRECTLY from global
//          (81 independent unrolled dword loads -> full MLP, no LDS staging,
//          no barriers) + refine + clip + direct LDS compaction (the
//          round-1/3-verified order-invariant pattern).
// Phase B: verbatim round-3 nms_v5 body (rank-sort + bitmask NMS + emit),
//          strides upgraded 256 -> 512.
// LDS ~82 KB, no aliasing. 16 blocks, 1 block/CU.
__global__ __launch_bounds__(NTHREADS) void detect_fused_v7(
    const float* __restrict__ rois, const float* __restrict__ probs,
    const float* __restrict__ deltas, const float* __restrict__ window,
    float* __restrict__ out)
{
    const int b = blockIdx.x;
    const int tid = threadIdx.x;

    __shared__ float s_cbox[N_ROIS][4];        // candidates (compaction order)
    __shared__ float s_csc[N_ROIS];
    __shared__ short s_cidx[N_ROIS];           // original roi idx (tie-break)
    __shared__ unsigned char s_ccls[N_ROIS];
    __shared__ float s_sbox[N_ROIS][4];        // sorted by (score desc, idx asc)
    __shared__ float s_ssc[N_ROIS];
    __shared__ unsigned char s_scls[N_ROIS];
    __shared__ unsigned char s_kept[N_ROIS];
    __shared__ short s_bucket[N_ROIS];         // per-class lists of sorted rank
    __shared__ short s_pos[N_ROIS];            // rank -> position within class
    __shared__ unsigned long long s_sup[N_ROIS][SUP_WORDS];   // 32 KB
    __shared__ int s_cnt[NUM_CLASSES];
    __shared__ int s_off[NUM_CLASSES];
    __shared__ int s_C;

    if (tid == 0) s_C = 0;
    if (tid < NUM_CLASSES) s_cnt[tid] = 0;

    // zero this batch's output rows (d_out is poisoned before every replay)
    for (int i = tid; i < DET_MAX * 6; i += NTHREADS)
        out[(size_t)b * DET_MAX * 6 + i] = 0.0f;

    const float4 wv = ((const float4*)window)[b];   // per-block uniform
    __syncthreads();    // s_C / s_cnt init visible before compaction atomics

    // ---------------- phase A: argmax + refine + compact ----------------
    for (int r = tid; r < N_ROIS; r += NTHREADS) {
        const size_t gidx = (size_t)b * N_ROIS + r;
        const float* p = probs + gidx * NUM_CLASSES;

        // 4-chain argmax over 81 probs; lowest-index maximum (== jnp.argmax).
        // Fully unrolled -> 81 independent global dword loads in flight.
        float bs0 = p[0], bs1 = p[1], bs2 = p[2], bs3 = p[3];
        int ib0 = 0, ib1 = 1, ib2 = 2, ib3 = 3;
        #pragma unroll
        for (int c = 4; c <= 76; c += 4) {
            float v0 = p[c], v1 = p[c + 1], v2 = p[c + 2], v3 = p[c + 3];
            if (v0 > bs0) { bs0 = v0; ib0 = c; }
            if (v1 > bs1) { bs1 = v1; ib1 = c + 1; }
            if (v2 > bs2) { bs2 = v2; ib2 = c + 2; }
            if (v3 > bs3) { bs3 = v3; ib3 = c + 3; }
        }
        { float v = p[80]; if (v > bs0) { bs0 = v; ib0 = 80; } }
        if (bs1 > bs0 || (bs1 == bs0 && ib1 < ib0)) { bs0 = bs1; ib0 = ib1; }
        if (bs3 > bs2 || (bs3 == bs2 && ib3 < ib2)) { bs2 = bs3; ib2 = ib3; }
        if (bs2 > bs0 || (bs2 == bs0 && ib2 < ib0)) { bs0 = bs2; ib0 = ib2; }
        const float bs = bs0;
        const int best = ib0;

        if ((best > 0) && (bs >= MIN_CONF)) {
            const float4 dd = ((const float4*)deltas)[gidx * NUM_CLASSES + best];
            float dy = dd.x * 0.1f, dx = dd.y * 0.1f, dh = dd.z * 0.2f, dw = dd.w * 0.2f;

            const float4 rr = ((const float4*)rois)[gidx];
            float y1 = rr.x, x1 = rr.y, y2 = rr.z, x2 = rr.w;
            float h = y2 - y1, w = x2 - x1;
            float cy = y1 + 0.5f * h, cx = x1 + 0.5f * w;
            cy += dy * h;
            cx += dx * w;
            h *= expf(dh);
            w *= expf(dw);
            float ny1 = cy - 0.5f * h;
            float nx1 = cx - 0.5f * w;
            float ny2 = ny1 + h;   // matches reference: y2 = y1 + h
            float nx2 = nx1 + w;

            ny1 = fminf(fmaxf(ny1, wv.x), wv.z);
            nx1 = fminf(fmaxf(nx1, wv.y), wv.w);
            ny2 = fminf(fmaxf(ny2, wv.x), wv.z);
            nx2 = fminf(fmaxf(nx2, wv.y), wv.w);

            const int k = atomicAdd(&s_C, 1);
            s_csc[k] = bs;
            s_cidx[k] = (short)r;
            s_ccls[k] = (unsigned char)best;
            atomicAdd(&s_cnt[best], 1);
            ((float4*)s_cbox)[k] = make_float4(ny1, nx1, ny2, nx2);
        }
    }
    __syncthreads();
    const int C = s_C;

    if (tid == 0) {      // class bucket offsets (81 trivial serial iters)
        int acc = 0;
        for (int c = 0; c < NUM_CLASSES; ++c) { s_off[c] = acc; acc += s_cnt[c]; }
    }
    __syncthreads();

    // ---- rank-sort by (score desc, idx asc) + direct class-bucket scatter ----
    // (sc, idx) is a strict total order -> deterministic despite atomic
    // compaction order; crank = rank restricted to this candidate's class.
    for (int k = tid; k < C; k += NTHREADS) {
        float sk = s_csc[k];
        int ik = s_cidx[k];
        int ck = s_ccls[k];
        int rank = 0, crank = 0;
        for (int j = 0; j < C; ++j) {   // broadcast LDS reads
            float sj = s_csc[j];
            int before = (sj > sk) | ((sj == sk) & (s_cidx[j] < ik));
            rank += before;
            crank += before & (s_ccls[j] == ck);
        }
        s_ssc[rank] = sk;
        s_scls[rank] = (unsigned char)ck;
        ((float4*)s_sbox)[rank] = ((const float4*)s_cbox)[k];
        s_kept[rank] = 0;
        s_pos[rank] = (short)crank;
        s_bucket[s_off[ck] + crank] = (short)rank;
    }
    __syncthreads();

    // ---- phase 3a: parallel suppression-bit matrix ----
    // slot u holds class-position a; set bit q (a < q < m) iff IoU > thresh.
    for (int u = tid; u < C; u += NTHREADS) {
        const int i = s_bucket[u];              // rank
        const int c = s_scls[i];
        const int m = s_cnt[c];
        if (m > 64 * SUP_WORDS) continue;       // fallback class: rows unused
        const int a = s_pos[i];
        const int off = u - a;                  // == s_off[c]
        const float b0 = s_sbox[i][0], b1 = s_sbox[i][1];
        const float b2 = s_sbox[i][2], b3 = s_sbox[i][3];
        const float area_b = (b2 - b0) * (b3 - b1);
        #pragma unroll
        for (int qw = 0; qw < SUP_WORDS; ++qw) {
            unsigned long long w = 0;
            const int qlo = (qw << 6) > (a + 1) ? (qw << 6) : (a + 1);
            const int qhi = m < ((qw << 6) + 64) ? m : ((qw << 6) + 64);
            for (int q = qlo; q < qhi; ++q) {
                const int j = s_bucket[off + q];
                const float a0 = s_sbox[j][0], a1 = s_sbox[j][1];
                const float a2 = s_sbox[j][2], a3 = s_sbox[j][3];
                float yy1 = fmaxf(a0, b0);
                float xx1 = fmaxf(a1, b1);
                float yy2 = fminf(a2, b2);
                float xx2 = fminf(a3, b3);
                float inter = fmaxf(yy2 - yy1, 0.0f) * fmaxf(xx2 - xx1, 0.0f);
                float area_a = (a2 - a0) * (a3 - a1);
                float uni = area_a + area_b - inter;
                w |= (unsigned long long)(inter / fmaxf(uni, 1e-10f) > NMS_THRESH)
                     << (q & 63);
            }
            s_sup[u][qw] = w;
        }
    }
    __syncthreads();

    // ---- phase 3b: per-class greedy scan (bitmask; classes in parallel) ----
    if (tid >= 1 && tid < NUM_CLASSES) {
        const int off = s_off[tid];
        const int m = s_cnt[tid];
        if (m <= 64 * SUP_WORDS) {
            unsigned long long r0 = 0, r1 = 0, r2 = 0, r3 = 0;
            int cnt = 0;
            for (int a = 0; a < m; ++a) {
                if (cnt >= DET_MAX) break;
                const unsigned long long rb =
                    (a < 64) ? r0 : (a < 128) ? r1 : (a < 192) ? r2 : r3;
                if ((rb >> (a & 63)) & 1ull) continue;   // suppressed by a kept box
                const int i = s_bucket[off + a];
                s_kept[i] = 1; ++cnt;
                r0 |= s_sup[off + a][0];
                r1 |= s_sup[off + a][1];
                r2 |= s_sup[off + a][2];
                r3 |= s_sup[off + a][3];
            }
        } else {
            // verbatim serial greedy (correct for any m; never expected)
            int kept_cnt = 0;
            for (int a = 0; a < m; ++a) {
                if (kept_cnt >= DET_MAX) break;
                int i = s_bucket[off + a];
                float b0 = s_sbox[i][0], b1 = s_sbox[i][1];
                float b2 = s_sbox[i][2], b3 = s_sbox[i][3];
                float area_b = (b2 - b0) * (b3 - b1);
                bool sup = false;
                for (int q = 0; q < a; ++q) {
                    int j = s_bucket[off + q];
                    if (!s_kept[j]) continue;
                    float a0 = s_sbox[j][0], a1 = s_sbox[j][1];
                    float a2 = s_sbox[j][2], a3 = s_sbox[j][3];
                    float yy1 = fmaxf(a0, b0);
                    float xx1 = fmaxf(a1, b1);
                    float yy2 = fminf(a2, b2);
                    float xx2 = fminf(a3, b3);
                    float inter = fmaxf(yy2 - yy1, 0.0f) * fmaxf(xx2 - xx1, 0.0f);
                    float area_a = (a2 - a0) * (a3 - a1);
                    float uni = area_a + area_b - inter;
                    if (inter / fmaxf(uni, 1e-10f) > NMS_THRESH) { sup = true; break; }
                }
                if (!sup) { s_kept[i] = 1; ++kept_cnt; }
            }
        }
    }
    __syncthreads();

    // ---- emit: slot = prefix count of kept in sorted order (== top_k order) ----
    for (int i = tid; i < C; i += NTHREADS) {
        if (s_kept[i]) {
            int slot = 0;
            for (int j = 0; j < i; ++j) slot += s_kept[j];
            if (slot < DET_MAX) {
                float* o = out + (size_t)b * DET_MAX * 6 + slot * 6;
                o[0] = s_sbox[i][0];
                o[1] = s_sbox[i][1];
                o[2] = s_sbox[i][2];
                o[3] = s_sbox[i][3];
                o[4] = (float)s_scls[i];
                o[5] = s_ssc[i];
            }
        }
    }
}

extern "C" void kernel_launch(void* const* d_in, const int* in_sizes, int n_in,
                              void* d_out, int out_size, void* d_ws, size_t ws_size,
                              hipStream_t stream) {
    const float* rois      = (const float*)d_in[0];
    const float* fpn_class = (const float*)d_in[1];
    const float* fpn_bbox  = (const float*)d_in[2];
    const float* window    = (const float*)d_in[3];
    float* out = (float*)d_out;
    (void)d_ws; (void)ws_size;

    detect_fused_v7<<<BATCH, NTHREADS, 0, stream>>>(
        rois, fpn_class, fpn_bbox, window, out);
}

// Round 5
// 85.612 us; speedup vs baseline: 1.0265x; 1.0265x over previous
//
#include <hip/hip_runtime.h>
#include <math.h>

#define BATCH 16
#define N_ROIS 1000
#define NUM_CLASSES 81
#define DET_MAX 100
#define MIN_CONF 0.7f
#define NMS_THRESH 0.3f

// ---------------- Kernel A: per-thread argmax + refine + clip (no LDS) --------
// 1 ROI per thread, 63 blocks x 256 threads. Probs row read directly from
// global as 81 unrolled independent dword loads (sequential c => same 64B line
// 15/16 of the time => L1-resident; inputs L3-resident across replays).
// No staging, no barrier, no idle lanes. Argmax math byte-identical to the
// verified 4-chain (lowest-index maximum == jnp.argmax).
__global__ __launch_bounds__(256) void refine_v8(
    const float* __restrict__ rois, const float* __restrict__ probs,
    const float* __restrict__ deltas, const float* __restrict__ window,
    float* __restrict__ ws_box, float* __restrict__ ws_score, int* __restrict__ ws_cls)
{
    const int idx = blockIdx.x * 256 + threadIdx.x;   // flat ROI id
    if (idx >= BATCH * N_ROIS) return;
    const int b = idx / N_ROIS;

    const float* p = probs + (size_t)idx * NUM_CLASSES;

    // 4-chain argmax over 81 probs; lowest-index maximum (== jnp.argmax)
    float bs0 = p[0], bs1 = p[1], bs2 = p[2], bs3 = p[3];
    int ib0 = 0, ib1 = 1, ib2 = 2, ib3 = 3;
    #pragma unroll
    for (int c = 4; c <= 76; c += 4) {
        float v0 = p[c], v1 = p[c + 1], v2 = p[c + 2], v3 = p[c + 3];
        if (v0 > bs0) { bs0 = v0; ib0 = c; }
        if (v1 > bs1) { bs1 = v1; ib1 = c + 1; }
        if (v2 > bs2) { bs2 = v2; ib2 = c + 2; }
        if (v3 > bs3) { bs3 = v3; ib3 = c + 3; }
    }
    { float v = p[80]; if (v > bs0) { bs0 = v; ib0 = 80; } }
    if (bs1 > bs0 || (bs1 == bs0 && ib1 < ib0)) { bs0 = bs1; ib0 = ib1; }
    if (bs3 > bs2 || (bs3 == bs2 && ib3 < ib2)) { bs2 = bs3; ib2 = ib3; }
    if (bs2 > bs0 || (bs2 == bs0 && ib2 < ib0)) { bs0 = bs2; ib0 = ib2; }
    const float bs = bs0;
    const int best = ib0;

    const bool keep = (best > 0) && (bs >= MIN_CONF);
    ws_score[idx] = keep ? bs : -1.0f;

    if (keep) {
        const float4 dd = ((const float4*)deltas)[(size_t)idx * NUM_CLASSES + best];
        float dy = dd.x * 0.1f, dx = dd.y * 0.1f, dh = dd.z * 0.2f, dw = dd.w * 0.2f;

        const float4 rr = ((const float4*)rois)[idx];
        float y1 = rr.x, x1 = rr.y, y2 = rr.z, x2 = rr.w;
        float h = y2 - y1, w = x2 - x1;
        float cy = y1 + 0.5f * h, cx = x1 + 0.5f * w;
        cy += dy * h;
        cx += dx * w;
        h *= expf(dh);
        w *= expf(dw);
        float ny1 = cy - 0.5f * h;
        float nx1 = cx - 0.5f * w;
        float ny2 = ny1 + h;   // matches reference: y2 = y1 + h
        float nx2 = nx1 + w;

        const float* win = window + b * 4;
        float wy1 = win[0], wx1 = win[1], wy2 = win[2], wx2 = win[3];
        ny1 = fminf(fmaxf(ny1, wy1), wy2);
        nx1 = fminf(fmaxf(nx1, wx1), wx2);
        ny2 = fminf(fmaxf(ny2, wy1), wy2);
        nx2 = fminf(fmaxf(nx2, wx1), wx2);

        ((float4*)ws_box)[idx] = make_float4(ny1, nx1, ny2, nx2);
        ws_cls[idx] = best;
    }
}

// ---------------- Kernel B: VERBATIM round-0 nms_v4 (measured 85.0, absmax 0) -
__global__ __launch_bounds__(256) void nms_v4(
    const float* __restrict__ ws_box, const float* __restrict__ ws_score,
    const int* __restrict__ ws_cls, float* __restrict__ out)
{
    const int b = blockIdx.x;
    const int tid = threadIdx.x;

    __shared__ float s_cbox[N_ROIS][4];        // candidates (compaction order)
    __shared__ float s_csc[N_ROIS];
    __shared__ short s_cidx[N_ROIS];           // original roi idx (tie-break)
    __shared__ unsigned char s_ccls[N_ROIS];
    __shared__ float s_sbox[N_ROIS][4];        // sorted by (score desc, idx asc)
    __shared__ float s_ssc[N_ROIS];
    __shared__ unsigned char s_scls[N_ROIS];
    __shared__ unsigned char s_kept[N_ROIS];
    __shared__ short s_bucket[N_ROIS];         // per-class lists of sorted idx
    __shared__ int s_cnt[NUM_CLASSES];
    __shared__ int s_off[NUM_CLASSES];
    __shared__ int s_C;

    if (tid == 0) s_C = 0;
    if (tid < NUM_CLASSES) s_cnt[tid] = 0;

    // zero this batch's output rows (d_out is poisoned before every replay)
    for (int i = tid; i < DET_MAX * 6; i += 256)
        out[(size_t)b * DET_MAX * 6 + i] = 0.0f;
    __syncthreads();

    // ---- compact candidates (score >= 0) into LDS ----
    for (int i = tid; i < N_ROIS; i += 256) {
        float sc = ws_score[b * N_ROIS + i];
        if (sc >= 0.0f) {
            int k = atomicAdd(&s_C, 1);
            s_csc[k] = sc;
            s_cidx[k] = (short)i;
            int c = ws_cls[b * N_ROIS + i];
            s_ccls[k] = (unsigned char)c;
            atomicAdd(&s_cnt[c], 1);
            float4 bb = ((const float4*)ws_box)[b * N_ROIS + i];
            s_cbox[k][0] = bb.x; s_cbox[k][1] = bb.y;
            s_cbox[k][2] = bb.z; s_cbox[k][3] = bb.w;
        }
    }
    __syncthreads();
    const int C = s_C;

    if (tid == 0) {      // class bucket offsets
        int acc = 0;
        for (int c = 0; c < NUM_CLASSES; ++c) { s_off[c] = acc; acc += s_cnt[c]; }
    }
    __syncthreads();

    // ---- rank-sort by (score desc, idx asc) + direct class-bucket scatter ----
    for (int k = tid; k < C; k += 256) {
        float sk = s_csc[k];
        int ik = s_cidx[k];
        int ck = s_ccls[k];
        int rank = 0, crank = 0;
        for (int j = 0; j < C; ++j) {   // broadcast LDS reads
            float sj = s_csc[j];
            int before = (sj > sk) | ((sj == sk) & (s_cidx[j] < ik));
            rank += before;
            crank += before & (s_ccls[j] == ck);
        }
        s_ssc[rank] = sk;
        s_scls[rank] = (unsigned char)ck;
        s_sbox[rank][0] = s_cbox[k][0];
        s_sbox[rank][1] = s_cbox[k][1];
        s_sbox[rank][2] = s_cbox[k][2];
        s_sbox[rank][3] = s_cbox[k][3];
        s_kept[rank] = 0;
        s_bucket[s_off[ck] + crank] = (short)rank;
    }
    __syncthreads();

    // ---- per-class greedy NMS, all classes in parallel ----
    if (tid >= 1 && tid < NUM_CLASSES) {
        const int off = s_off[tid];
        const int m = s_cnt[tid];
        int kept_cnt = 0;
        for (int a = 0; a < m; ++a) {
            if (kept_cnt >= DET_MAX) break;
            int i = s_bucket[off + a];
            float b0 = s_sbox[i][0], b1 = s_sbox[i][1];
            float b2 = s_sbox[i][2], b3 = s_sbox[i][3];
            float area_b = (b2 - b0) * (b3 - b1);
            bool sup = false;
            for (int q = 0; q < a; ++q) {
                int j = s_bucket[off + q];
                if (!s_kept[j]) continue;
                float a0 = s_sbox[j][0], a1 = s_sbox[j][1];
                float a2 = s_sbox[j][2], a3 = s_sbox[j][3];
                float yy1 = fmaxf(a0, b0);
                float xx1 = fmaxf(a1, b1);
                float yy2 = fminf(a2, b2);
                float xx2 = fminf(a3, b3);
                float inter = fmaxf(yy2 - yy1, 0.0f) * fmaxf(xx2 - xx1, 0.0f);
                float area_a = (a2 - a0) * (a3 - a1);
                float uni = area_a + area_b - inter;
                if (inter / fmaxf(uni, 1e-10f) > NMS_THRESH) { sup = true; break; }
            }
            if (!sup) { s_kept[i] = 1; ++kept_cnt; }
        }
    }
    __syncthreads();

    // ---- emit: slot = prefix count of kept in sorted order (== top_k order) ----
    for (int i = tid; i < C; i += 256) {
        if (s_kept[i]) {
            int slot = 0;
            for (int j = 0; j < i; ++j) slot += s_kept[j];
            if (slot < DET_MAX) {
                float* o = out + (size_t)b * DET_MAX * 6 + slot * 6;
                o[0] = s_sbox[i][0];
                o[1] = s_sbox[i][1];
                o[2] = s_sbox[i][2];
                o[3] = s_sbox[i][3];
                o[4] = (float)s_scls[i];
                o[5] = s_ssc[i];
            }
        }
    }
}

extern "C" void kernel_launch(void* const* d_in, const int* in_sizes, int n_in,
                              void* d_out, int out_size, void* d_ws, size_t ws_size,
                              hipStream_t stream) {
    const float* rois      = (const float*)d_in[0];
    const float* fpn_class = (const float*)d_in[1];
    const float* fpn_bbox  = (const float*)d_in[2];
    const float* window    = (const float*)d_in[3];
    float* out = (float*)d_out;

    // workspace layout: boxes | scores | class ids  (384 KB of d_ws)
    float* ws_box   = (float*)d_ws;                        // BATCH*N_ROIS*4
    float* ws_score = ws_box + (size_t)BATCH * N_ROIS * 4; // BATCH*N_ROIS
    int*   ws_cls   = (int*)(ws_score + (size_t)BATCH * N_ROIS);

    const int nblocks = (BATCH * N_ROIS + 255) / 256;      // 63
    refine_v8<<<nblocks, 256, 0, stream>>>(
        rois, fpn_class, fpn_bbox, window, ws_box, ws_score, ws_cls);
    nms_v4<<<BATCH, 256, 0, stream>>>(ws_box, ws_score, ws_cls, out);
}